// Round 2
// baseline (7399.323 us; speedup 1.0000x reference)
//
#include <hip/hip_runtime.h>

#define NN 50000
#define NE 800000
#define DN 160
#define DE 32
#define TE 64
#define NB 8

__global__ __launch_bounds__(256) void zero_kernel(float* __restrict__ T,
                                                   float* __restrict__ deg) {
    int i = blockIdx.x * 256 + threadIdx.x;
    if (i < NN * DN) T[i] = 0.0f;
    if (i < NN) deg[i] = 0.0f;
}

__global__ __launch_bounds__(320) void edge_kernel(
    const float* __restrict__ x, const int* __restrict__ eidx,
    const float* __restrict__ ea,
    const float* __restrict__ W1, const float* __restrict__ W2,
    const float* __restrict__ W3, const float* __restrict__ W4,
    float* __restrict__ T, float* __restrict__ deg)
{
    __shared__ float xls[TE][161];   // node row per edge, stride 161 (gcd(161,32)=1)
    __shared__ float els[TE][33];    // edge attrs, stride 33
    __shared__ int rowls[TE];
    __shared__ int colls[TE];

    const int t = threadIdx.x;
    const int base = blockIdx.x * TE;

    if (t < TE) {
        rowls[t] = eidx[base + t];        // int32 per harness convention
        colls[t] = eidx[NE + base + t];
    }
    __syncthreads();

    // gather node rows: 64 edges x 40 float4
    for (int j = t; j < TE * 40; j += 320) {
        int m = j / 40, q = j - m * 40;
        const float4 v = *reinterpret_cast<const float4*>(x + (size_t)colls[m] * DN + q * 4);
        xls[m][q*4+0] = v.x; xls[m][q*4+1] = v.y; xls[m][q*4+2] = v.z; xls[m][q*4+3] = v.w;
    }
    // edge attrs: 64 x 8 float4
    for (int j = t; j < TE * 8; j += 320) {
        int m = j >> 3, q = j & 7;
        const float4 v = *reinterpret_cast<const float4*>(ea + (size_t)(base + m) * DE + q * 4);
        els[m][q*4+0] = v.x; els[m][q*4+1] = v.y; els[m][q*4+2] = v.z; els[m][q*4+3] = v.w;
    }
    __syncthreads();

    if (t < TE) atomicAdd(&deg[rowls[t]], 1.0f);

    const int lane = t & 63;
    const int wv = __builtin_amdgcn_readfirstlane(t >> 6);  // uniform wave id
    const int row = rowls[lane];

    float acc[32];
    #pragma unroll
    for (int j = 0; j < 32; ++j) acc[j] = 0.0f;

    if (wv < 2) {
        // ---- scalar outputs, cols [cg, cg+32) ----
        const int cg = wv * 32;
        float es[8];
        #pragma unroll
        for (int b = 0; b < 8; ++b) es[b] = els[lane][b];

        // path (0e,0e->0e): z1[a,b] = xs[a]*es[b] against W1
        for (int a = 0; a < 64; ++a) {
            const float xa = xls[lane][a];
            #pragma unroll
            for (int b = 0; b < 8; ++b) {
                const float p = xa * es[b];
                const float* __restrict__ w = W1 + ((a * 8 + b) * 64 + cg);
                #pragma unroll
                for (int j = 0; j < 32; ++j) acc[j] = fmaf(p, w[j], acc[j]);
            }
        }
        // path (1o,1o->0e): z2[a,b] = dot(xv[a],ev[b]) against W2 (rel scale sqrt(2/3))
        float ev[24];
        #pragma unroll
        for (int q = 0; q < 24; ++q) ev[q] = els[lane][8 + q];
        const float r2 = 0.8164965809277260f;  // (1/(sqrt3*16)) / (1/(16*sqrt2))
        for (int a = 0; a < 32; ++a) {
            const float x0 = xls[lane][64 + a*3 + 0];
            const float x1 = xls[lane][64 + a*3 + 1];
            const float x2 = xls[lane][64 + a*3 + 2];
            #pragma unroll
            for (int b = 0; b < 8; ++b) {
                float p = x0 * ev[b*3+0];
                p = fmaf(x1, ev[b*3+1], p);
                p = fmaf(x2, ev[b*3+2], p);
                p *= r2;
                const float* __restrict__ w = W2 + ((a * 8 + b) * 64 + cg);
                #pragma unroll
                for (int j = 0; j < 32; ++j) acc[j] = fmaf(p, w[j], acc[j]);
            }
        }
        const float sc = 1.0f / 32.0f;  // (1/(16*sqrt2)) * (1/sqrt2)
        #pragma unroll
        for (int j = 0; j < 32; ++j)
            atomicAdd(&T[(size_t)row * DN + cg + j], acc[j] * sc);
    } else {
        // ---- vector outputs, plane i = wv-2, c in [0,32) ----
        const int i = wv - 2;
        float es[8], evi[8];
        #pragma unroll
        for (int b = 0; b < 8; ++b) { es[b] = els[lane][b]; evi[b] = els[lane][8 + b*3 + i]; }

        // path (0e,1o->1o): xs[a]*ev[b][i] against W3
        for (int a = 0; a < 64; ++a) {
            const float xa = xls[lane][a];
            #pragma unroll
            for (int b = 0; b < 8; ++b) {
                const float p = xa * evi[b];
                const float* __restrict__ w = W3 + ((a * 8 + b) * 32);
                #pragma unroll
                for (int j = 0; j < 32; ++j) acc[j] = fmaf(p, w[j], acc[j]);
            }
        }
        // path (1o,0e->1o): xv[a][i]*es[b] against W4 (rel scale sqrt2)
        const float r4 = 1.4142135623730951f;
        for (int a = 0; a < 32; ++a) {
            const float xai = xls[lane][64 + a*3 + i];
            #pragma unroll
            for (int b = 0; b < 8; ++b) {
                const float p = xai * es[b] * r4;
                const float* __restrict__ w = W4 + ((a * 8 + b) * 32);
                #pragma unroll
                for (int j = 0; j < 32; ++j) acc[j] = fmaf(p, w[j], acc[j]);
            }
        }
        const float sc = 1.0f / 32.0f;
        #pragma unroll
        for (int j = 0; j < 32; ++j)
            atomicAdd(&T[(size_t)row * DN + 64 + j*3 + i], acc[j] * sc);
    }
}

// T == d_out: read T rows (the tp-accumulator), overwrite with final output.
__global__ __launch_bounds__(256) void node_kernel(
    const float* __restrict__ x, float* __restrict__ T,
    const float* __restrict__ deg,
    const float* __restrict__ Wm, const float* __restrict__ bm,
    const float* __restrict__ Wu, const float* __restrict__ bu)
{
    __shared__ float trow[NB][161];
    __shared__ float xrow[NB][161];
    __shared__ float arow[NB][161];
    const int t = threadIdx.x;
    const int nb = blockIdx.x * NB;

    for (int j = t; j < NB * 40; j += 256) {
        int m = j / 40, q = j - m * 40;
        const float4 a = *reinterpret_cast<const float4*>(T + (size_t)(nb + m) * DN + q * 4);
        const float4 b = *reinterpret_cast<const float4*>(x + (size_t)(nb + m) * DN + q * 4);
        trow[m][q*4+0]=a.x; trow[m][q*4+1]=a.y; trow[m][q*4+2]=a.z; trow[m][q*4+3]=a.w;
        xrow[m][q*4+0]=b.x; xrow[m][q*4+1]=b.y; xrow[m][q*4+2]=b.z; xrow[m][q*4+3]=b.w;
    }
    __syncthreads();

    const int n = t & (NB - 1);
    const int h0 = t >> 3;     // 0..31
    const float dg = deg[nb + n];

    // agg = T@Wm + deg*bm
    #pragma unroll
    for (int ii = 0; ii < 5; ++ii) {
        const int h = h0 + 32 * ii;
        float s = dg * bm[h];
        for (int k = 0; k < DN; ++k) s = fmaf(trow[n][k], Wm[k * DN + h], s);
        arow[n][h] = s;
    }
    __syncthreads();

    // out = x + [x, agg] @ Wu + bu
    #pragma unroll
    for (int ii = 0; ii < 5; ++ii) {
        const int c = h0 + 32 * ii;
        float s = bu[c];
        for (int k = 0; k < DN; ++k) s = fmaf(xrow[n][k], Wu[k * DN + c], s);
        for (int k = 0; k < DN; ++k) s = fmaf(arow[n][k], Wu[(DN + k) * DN + c], s);
        T[(size_t)(nb + n) * DN + c] = xrow[n][c] + s;
    }
}

extern "C" void kernel_launch(void* const* d_in, const int* in_sizes, int n_in,
                              void* d_out, int out_size, void* d_ws, size_t ws_size,
                              hipStream_t stream) {
    const float* xf   = (const float*)d_in[0];
    const int*   eidx = (const int*)d_in[1];   // int32 per harness convention
    const float* ea   = (const float*)d_in[2];
    // d_in[3] (node_attr_scalar_raw) unused by the reference
    const float* W1 = (const float*)d_in[4];
    const float* W2 = (const float*)d_in[5];
    const float* W3 = (const float*)d_in[6];
    const float* W4 = (const float*)d_in[7];
    const float* Wm = (const float*)d_in[8];
    const float* bm = (const float*)d_in[9];
    const float* Wu = (const float*)d_in[10];
    const float* bu = (const float*)d_in[11];

    float* out = (float*)d_out;   // doubles as the tp-accumulator T
    float* deg = (float*)d_ws;    // 50000 floats of scratch

    zero_kernel<<<(NN * DN + 255) / 256, 256, 0, stream>>>(out, deg);
    edge_kernel<<<NE / TE, 320, 0, stream>>>(xf, eidx, ea, W1, W2, W3, W4, out, deg);
    node_kernel<<<NN / NB, 256, 0, stream>>>(xf, out, deg, Wm, bm, Wu, bu);
}

// Round 3
// 1440.561 us; speedup vs baseline: 5.1364x; 5.1364x over previous
//
#include <hip/hip_runtime.h>
#include <hip/hip_bf16.h>

#define NN 50000
#define NE 800000
#define DN 160
#define DE 32
#define NB 8

typedef __attribute__((ext_vector_type(8))) short bf16x8;
typedef __attribute__((ext_vector_type(4))) float f32x4;

#define R2 0.81649658092772603f   /* sqrt(2/3): W2 rel scale */
#define R4 1.41421356237309515f   /* sqrt(2):   W4 rel scale */
#define SC (1.0f/32.0f)           /* global scale folded into weights */

__device__ __forceinline__ short bfbits(float f) {
    union { __hip_bfloat16 h; short s; } u;
    u.h = __float2bfloat16(f);
    return u.s;
}

__global__ __launch_bounds__(256) void zero_kernel(float* __restrict__ T,
                                                   float* __restrict__ deg) {
    int i = blockIdx.x * 256 + threadIdx.x;
    if (i < NN * DN) T[i] = 0.0f;
    if (i < NN) deg[i] = 0.0f;
}

// Pre-convert W1..W4 (fp32) into bf16, pre-scaled, laid out in MFMA
// 16x16x32 B-fragment order: elem id = ((n16*24 + t)*64 + lane)*8 + j
// where col = n16*16 + (lane&15), k = 32t + 8*(lane>>4) + j.
// K-order: k<512 -> path A (a=k>>3, b=k&7); k>=512 -> path B.
// s-part (49152 elems, cols 0..63): W1 then W2. v-part (24576, cols 0..31): W3 then W4.
__global__ __launch_bounds__(256) void wprep_kernel(
    const float* __restrict__ W1, const float* __restrict__ W2,
    const float* __restrict__ W3, const float* __restrict__ W4,
    unsigned short* __restrict__ Wbf)
{
    int id = blockIdx.x * 256 + threadIdx.x;   // 73728 total
    float w;
    if (id < 49152) {
        int j = id & 7, l = (id >> 3) & 63, t = (id >> 9) % 24, n16 = id / 12288;
        int c = n16 * 16 + (l & 15);
        int k = 32 * t + 8 * (l >> 4) + j;
        if (k < 512) { int a = k >> 3, b = k & 7; w = W1[(a*8+b)*64 + c] * SC; }
        else { int k2 = k - 512; int a = k2 >> 3, b = k2 & 7; w = W2[(a*8+b)*64 + c] * (R2*SC); }
    } else {
        int id2 = id - 49152;
        int j = id2 & 7, l = (id2 >> 3) & 63, t = (id2 >> 9) % 24, n16 = id2 / 12288;
        int c = n16 * 16 + (l & 15);
        int k = 32 * t + 8 * (l >> 4) + j;
        if (k < 512) { int a = k >> 3, b = k & 7; w = W3[(a*8+b)*32 + c] * SC; }
        else { int k2 = k - 512; int a = k2 >> 3, b = k2 & 7; w = W4[(a*8+b)*32 + c] * (R4*SC); }
    }
    union { __hip_bfloat16 h; unsigned short s; } u;
    u.h = __float2bfloat16(w);
    Wbf[id] = u.s;
}

// 64 edges/block, 4 waves; each wave owns 16 edges (rows), all 160 cols.
// A-frags formed in registers from LDS x + register e; B-frags loaded from
// pre-laid-out bf16 weights (uniform addrs -> L1/L2 broadcast).
__global__ __launch_bounds__(256) void edge_kernel(
    const float* __restrict__ x, const int* __restrict__ eidx,
    const float* __restrict__ ea, const unsigned short* __restrict__ Wbf,
    float* __restrict__ T, float* __restrict__ deg)
{
    __shared__ float xls[64][161];
    __shared__ float els[64][33];
    __shared__ int rowls[64];
    __shared__ int colls[64];

    const int t = threadIdx.x;
    const int base = blockIdx.x * 64;

    if (t < 64) {
        rowls[t] = eidx[base + t];
        colls[t] = eidx[NE + base + t];
    }
    __syncthreads();

    for (int j = t; j < 64 * 40; j += 256) {
        int m = j / 40, q = j - m * 40;
        const float4 v = *reinterpret_cast<const float4*>(x + (size_t)colls[m] * DN + q * 4);
        xls[m][q*4+0] = v.x; xls[m][q*4+1] = v.y; xls[m][q*4+2] = v.z; xls[m][q*4+3] = v.w;
    }
    for (int j = t; j < 64 * 8; j += 256) {
        int m = j >> 3, q = j & 7;
        const float4 v = *reinterpret_cast<const float4*>(ea + (size_t)(base + m) * DE + q * 4);
        els[m][q*4+0] = v.x; els[m][q*4+1] = v.y; els[m][q*4+2] = v.z; els[m][q*4+3] = v.w;
    }
    __syncthreads();

    if (t < 64) atomicAdd(&deg[rowls[t]], 1.0f);

    const int lane = t & 63;
    const int wv = t >> 6;        // 0..3
    const int r = lane & 15;      // A row / B col / C col
    const int g = lane >> 4;      // k-group
    const int er = wv * 16 + r;   // edge within block owning this lane's A row

    float es[8], ev[24];
    #pragma unroll
    for (int j = 0; j < 8; ++j) es[j] = els[er][j];
    #pragma unroll
    for (int j = 0; j < 24; ++j) ev[j] = els[er][8 + j];

    f32x4 accS[4], accV[3][2];
    #pragma unroll
    for (int n = 0; n < 4; ++n) accS[n] = (f32x4){0.f, 0.f, 0.f, 0.f};
    #pragma unroll
    for (int i = 0; i < 3; ++i)
        #pragma unroll
        for (int n = 0; n < 2; ++n) accV[i][n] = (f32x4){0.f, 0.f, 0.f, 0.f};

    const unsigned short* Ws = Wbf;          // s-part
    const unsigned short* Wv = Wbf + 49152;  // v-part

    for (int tt = 0; tt < 24; ++tt) {
        bf16x8 bS[4], bV[2];
        #pragma unroll
        for (int n = 0; n < 4; ++n)
            bS[n] = *reinterpret_cast<const bf16x8*>(Ws + ((size_t)(n * 24 + tt) * 64 + lane) * 8);
        #pragma unroll
        for (int n = 0; n < 2; ++n)
            bV[n] = *reinterpret_cast<const bf16x8*>(Wv + ((size_t)(n * 24 + tt) * 64 + lane) * 8);

        bf16x8 aS, aV0, aV1, aV2;
        if (tt < 16) {
            // 512-part: k = a*8+b, a = 4*tt+g, b = j
            const int a = 4 * tt + g;
            const float xa = xls[er][a];
            #pragma unroll
            for (int j = 0; j < 8; ++j) {
                aS[j]  = bfbits(xa * es[j]);            // z1 = xs[a]*es[b]
                aV0[j] = bfbits(xa * ev[j*3 + 0]);      // z3_i = xs[a]*ev[b][i]
                aV1[j] = bfbits(xa * ev[j*3 + 1]);
                aV2[j] = bfbits(xa * ev[j*3 + 2]);
            }
        } else {
            // 256-part: k-512 = a*8+b, a = 4*(tt-16)+g
            const int a = 4 * (tt - 16) + g;
            const float x0 = xls[er][64 + a*3 + 0];
            const float x1 = xls[er][64 + a*3 + 1];
            const float x2 = xls[er][64 + a*3 + 2];
            #pragma unroll
            for (int j = 0; j < 8; ++j) {
                float p = fmaf(x2, ev[j*3 + 2], fmaf(x1, ev[j*3 + 1], x0 * ev[j*3 + 0]));
                aS[j]  = bfbits(p);                     // z2 = xv[a].ev[b]  (r2 in W)
                aV0[j] = bfbits(x0 * es[j]);            // z4_i = xv[a][i]*es[b] (r4 in W)
                aV1[j] = bfbits(x1 * es[j]);
                aV2[j] = bfbits(x2 * es[j]);
            }
        }

        #pragma unroll
        for (int n = 0; n < 4; ++n)
            accS[n] = __builtin_amdgcn_mfma_f32_16x16x32_bf16(aS, bS[n], accS[n], 0, 0, 0);
        #pragma unroll
        for (int n = 0; n < 2; ++n) {
            accV[0][n] = __builtin_amdgcn_mfma_f32_16x16x32_bf16(aV0, bV[n], accV[0][n], 0, 0, 0);
            accV[1][n] = __builtin_amdgcn_mfma_f32_16x16x32_bf16(aV1, bV[n], accV[1][n], 0, 0, 0);
            accV[2][n] = __builtin_amdgcn_mfma_f32_16x16x32_bf16(aV2, bV[n], accV[2][n], 0, 0, 0);
        }
    }

    // C/D: col = lane&15 (=r), row = g*4 + reg  [m89 verified layout]
    #pragma unroll
    for (int reg = 0; reg < 4; ++reg) {
        const int erow = wv * 16 + g * 4 + reg;
        const int node = rowls[erow];
        float* Trow = T + (size_t)node * DN;
        #pragma unroll
        for (int n = 0; n < 4; ++n)
            atomicAdd(Trow + n * 16 + r, accS[n][reg]);
        #pragma unroll
        for (int i = 0; i < 3; ++i) {
            #pragma unroll
            for (int n = 0; n < 2; ++n)
                atomicAdd(Trow + 64 + (n * 16 + r) * 3 + i, accV[i][n][reg]);
        }
    }
}

// T == d_out: read T rows (tp-accumulator), overwrite with final output.
__global__ __launch_bounds__(256) void node_kernel(
    const float* __restrict__ x, float* __restrict__ T,
    const float* __restrict__ deg,
    const float* __restrict__ Wm, const float* __restrict__ bm,
    const float* __restrict__ Wu, const float* __restrict__ bu)
{
    __shared__ float trow[NB][161];
    __shared__ float xrow[NB][161];
    __shared__ float arow[NB][161];
    const int t = threadIdx.x;
    const int nb = blockIdx.x * NB;

    for (int j = t; j < NB * 40; j += 256) {
        int m = j / 40, q = j - m * 40;
        const float4 a = *reinterpret_cast<const float4*>(T + (size_t)(nb + m) * DN + q * 4);
        const float4 b = *reinterpret_cast<const float4*>(x + (size_t)(nb + m) * DN + q * 4);
        trow[m][q*4+0]=a.x; trow[m][q*4+1]=a.y; trow[m][q*4+2]=a.z; trow[m][q*4+3]=a.w;
        xrow[m][q*4+0]=b.x; xrow[m][q*4+1]=b.y; xrow[m][q*4+2]=b.z; xrow[m][q*4+3]=b.w;
    }
    __syncthreads();

    const int n = t & (NB - 1);
    const int h0 = t >> 3;     // 0..31
    const float dg = deg[nb + n];

    #pragma unroll
    for (int ii = 0; ii < 5; ++ii) {
        const int h = h0 + 32 * ii;
        float s = dg * bm[h];
        for (int k = 0; k < DN; ++k) s = fmaf(trow[n][k], Wm[k * DN + h], s);
        arow[n][h] = s;
    }
    __syncthreads();

    #pragma unroll
    for (int ii = 0; ii < 5; ++ii) {
        const int c = h0 + 32 * ii;
        float s = bu[c];
        for (int k = 0; k < DN; ++k) s = fmaf(xrow[n][k], Wu[k * DN + c], s);
        for (int k = 0; k < DN; ++k) s = fmaf(arow[n][k], Wu[(DN + k) * DN + c], s);
        T[(size_t)(nb + n) * DN + c] = xrow[n][c] + s;
    }
}

extern "C" void kernel_launch(void* const* d_in, const int* in_sizes, int n_in,
                              void* d_out, int out_size, void* d_ws, size_t ws_size,
                              hipStream_t stream) {
    const float* xf   = (const float*)d_in[0];
    const int*   eidx = (const int*)d_in[1];
    const float* ea   = (const float*)d_in[2];
    const float* W1 = (const float*)d_in[4];
    const float* W2 = (const float*)d_in[5];
    const float* W3 = (const float*)d_in[6];
    const float* W4 = (const float*)d_in[7];
    const float* Wm = (const float*)d_in[8];
    const float* bm = (const float*)d_in[9];
    const float* Wu = (const float*)d_in[10];
    const float* bu = (const float*)d_in[11];

    float* out = (float*)d_out;                       // tp-accumulator T
    float* deg = (float*)d_ws;                        // 200 KB
    unsigned short* Wbf = (unsigned short*)((char*)d_ws + 256 * 1024);  // 144 KB bf16 weights

    wprep_kernel<<<288, 256, 0, stream>>>(W1, W2, W3, W4, Wbf);
    zero_kernel<<<(NN * DN + 255) / 256, 256, 0, stream>>>(out, deg);
    edge_kernel<<<NE / 64, 256, 0, stream>>>(xf, eidx, ea, Wbf, out, deg);
    node_kernel<<<NN / NB, 256, 0, stream>>>(xf, out, deg, Wm, bm, Wu, bu);
}

// Round 4
// 966.313 us; speedup vs baseline: 7.6573x; 1.4908x over previous
//
#include <hip/hip_runtime.h>
#include <hip/hip_bf16.h>

#define NN 50000
#define NE 800000
#define DN 160
#define DE 32

typedef __attribute__((ext_vector_type(8))) short bf16x8;
typedef __attribute__((ext_vector_type(4))) float f32x4;
typedef __attribute__((ext_vector_type(4))) unsigned short u16x4;

#define R2 0.81649658092772603f   /* sqrt(2/3): W2 rel scale */
#define R4 1.41421356237309515f   /* sqrt(2):   W4 rel scale */
#define SC (1.0f/32.0f)           /* global scale folded into weights */

__device__ __forceinline__ unsigned short bfu16(float f) {
    union { __hip_bfloat16 h; unsigned short s; } u;
    u.h = __float2bfloat16(f);
    return u.s;
}
__device__ __forceinline__ short bfbits(float f) { return (short)bfu16(f); }
__device__ __forceinline__ float bf2f(unsigned short s) {
    union { float f; unsigned int u; } u;
    u.u = ((unsigned int)s) << 16;
    return u.f;
}

__global__ __launch_bounds__(256) void zero_kernel(float* __restrict__ T,
                                                   float* __restrict__ deg) {
    int i = blockIdx.x * 256 + threadIdx.x;
    if (i < NN * DN) T[i] = 0.0f;
    if (i < NN) deg[i] = 0.0f;
}

// ---- edge-TP weights: bf16, pre-scaled, MFMA 16x16x32 B-frag layout ----
// elem id = ((n16*24 + t)*64 + lane)*8 + j ; col = n16*16+(lane&15),
// k = 32t + 8*(lane>>4) + j.  k<512: path A (a=k>>3,b=k&7); k>=512: path B.
__global__ __launch_bounds__(256) void wprep_edge_kernel(
    const float* __restrict__ W1, const float* __restrict__ W2,
    const float* __restrict__ W3, const float* __restrict__ W4,
    unsigned short* __restrict__ Wbf)
{
    int id = blockIdx.x * 256 + threadIdx.x;   // 73728 total
    float w;
    if (id < 49152) {
        int j = id & 7, l = (id >> 3) & 63, t = (id >> 9) % 24, n16 = id / 12288;
        int c = n16 * 16 + (l & 15);
        int k = 32 * t + 8 * (l >> 4) + j;
        if (k < 512) { int a = k >> 3, b = k & 7; w = W1[(a*8+b)*64 + c] * SC; }
        else { int k2 = k - 512; int a = k2 >> 3, b = k2 & 7; w = W2[(a*8+b)*64 + c] * (R2*SC); }
    } else {
        int id2 = id - 49152;
        int j = id2 & 7, l = (id2 >> 3) & 63, t = (id2 >> 9) % 24, n16 = id2 / 12288;
        int c = n16 * 16 + (l & 15);
        int k = 32 * t + 8 * (l >> 4) + j;
        if (k < 512) { int a = k >> 3, b = k & 7; w = W3[(a*8+b)*32 + c] * SC; }
        else { int k2 = k - 512; int a = k2 >> 3, b = k2 & 7; w = W4[(a*8+b)*32 + c] * (R4*SC); }
    }
    Wbf[id] = bfu16(w);
}

// ---- Wc = Wm @ Wu_bot (fp32), bc = bm @ Wu_bot ----
__global__ __launch_bounds__(256) void wcomp_kernel(
    const float* __restrict__ Wm, const float* __restrict__ bm,
    const float* __restrict__ Wu, float* __restrict__ Wc, float* __restrict__ bc)
{
    int id = blockIdx.x * 256 + threadIdx.x;
    if (id < 160 * 160) {
        int k = id / 160, c = id % 160;
        float s = 0.0f;
        for (int h = 0; h < 160; ++h) s = fmaf(Wm[k*160 + h], Wu[(160 + h)*160 + c], s);
        Wc[id] = s;
    }
    if (id < 160) {
        float s = 0.0f;
        for (int h = 0; h < 160; ++h) s = fmaf(bm[h], Wu[(160 + h)*160 + id], s);
        bc[id] = s;
    }
}

// ---- node-GEMM weights: [Wu_top(160); Wc permuted to T's i-major layout] ----
// K=320 (10 k-tiles), N=160 (10 n-tiles). Same B-frag formula, 10 t-tiles.
__global__ __launch_bounds__(256) void wprep_node_kernel(
    const float* __restrict__ Wu, const float* __restrict__ Wc,
    unsigned short* __restrict__ Wn)
{
    int id = blockIdx.x * 256 + threadIdx.x;   // 51200 total
    if (id >= 51200) return;
    int j = id & 7, l = (id >> 3) & 63, tn = id >> 9;  // tn = n16*10 + tk
    int tk = tn % 10, n16 = tn / 10;
    int c = n16 * 16 + (l & 15);
    int k = 32 * tk + 8 * (l >> 4) + j;
    float w;
    if (k < 160) {
        w = Wu[k * 160 + c];
    } else {
        int tcol = k - 160;  // T-layout col: [0,64)=s ; 64+i*32+cc = v (i-major)
        int orig = (tcol < 64) ? tcol : 64 + ((tcol - 64) & 31) * 3 + ((tcol - 64) >> 5);
        w = Wc[orig * 160 + c];
    }
    Wn[id] = bfu16(w);
}

// ---- per-edge TP via MFMA; atomic scatter into T (s: std layout, v: i-major) ----
__global__ __launch_bounds__(256, 4) void edge_kernel(
    const float* __restrict__ x, const int* __restrict__ eidx,
    const float* __restrict__ ea, const unsigned short* __restrict__ Wbf,
    float* __restrict__ T, float* __restrict__ deg)
{
    __shared__ __align__(16) float xsls[64][66];            // xs fp32
    __shared__ __align__(16) unsigned short xvls[64][100];  // xv bf16 (96 used)
    __shared__ __align__(16) float els[64][33];             // edge attrs fp32
    __shared__ int rowls[64];
    __shared__ int colls[64];

    const int t = threadIdx.x;
    const int base = blockIdx.x * 64;

    if (t < 64) {
        rowls[t] = eidx[base + t];
        colls[t] = eidx[NE + base + t];
    }
    __syncthreads();

    for (int j = t; j < 64 * 40; j += 256) {
        int m = j / 40, q = j - m * 40;
        const float4 v = *reinterpret_cast<const float4*>(x + (size_t)colls[m] * DN + q * 4);
        if (q < 16) {
            xsls[m][q*4+0] = v.x; xsls[m][q*4+1] = v.y; xsls[m][q*4+2] = v.z; xsls[m][q*4+3] = v.w;
        } else {
            u16x4 p; p[0] = bfu16(v.x); p[1] = bfu16(v.y); p[2] = bfu16(v.z); p[3] = bfu16(v.w);
            *reinterpret_cast<u16x4*>(&xvls[m][q*4 - 64]) = p;
        }
    }
    for (int j = t; j < 64 * 8; j += 256) {
        int m = j >> 3, q = j & 7;
        const float4 v = *reinterpret_cast<const float4*>(ea + (size_t)(base + m) * DE + q * 4);
        els[m][q*4+0] = v.x; els[m][q*4+1] = v.y; els[m][q*4+2] = v.z; els[m][q*4+3] = v.w;
    }
    __syncthreads();

    if (t < 64) atomicAdd(&deg[rowls[t]], 1.0f);

    const int lane = t & 63;
    const int wv = t >> 6;        // 0..3
    const int r = lane & 15;      // A row / B col / C col
    const int g = lane >> 4;      // k-group
    const int er = wv * 16 + r;   // edge owning this lane's A row

    float es[8], ev[24];
    #pragma unroll
    for (int j = 0; j < 8; ++j) es[j] = els[er][j];
    #pragma unroll
    for (int j = 0; j < 24; ++j) ev[j] = els[er][8 + j];

    f32x4 accS[4], accV[3][2];
    #pragma unroll
    for (int n = 0; n < 4; ++n) accS[n] = (f32x4){0.f, 0.f, 0.f, 0.f};
    #pragma unroll
    for (int i = 0; i < 3; ++i)
        #pragma unroll
        for (int n = 0; n < 2; ++n) accV[i][n] = (f32x4){0.f, 0.f, 0.f, 0.f};

    const unsigned short* Ws = Wbf;          // s-part
    const unsigned short* Wv = Wbf + 49152;  // v-part

    for (int tt = 0; tt < 24; ++tt) {
        bf16x8 bS[4], bV[2];
        #pragma unroll
        for (int n = 0; n < 4; ++n)
            bS[n] = *reinterpret_cast<const bf16x8*>(Ws + ((size_t)(n * 24 + tt) * 64 + lane) * 8);
        #pragma unroll
        for (int n = 0; n < 2; ++n)
            bV[n] = *reinterpret_cast<const bf16x8*>(Wv + ((size_t)(n * 24 + tt) * 64 + lane) * 8);

        bf16x8 aS, aV0, aV1, aV2;
        if (tt < 16) {
            const int a = 4 * tt + g;
            const float xa = xsls[er][a];
            #pragma unroll
            for (int j = 0; j < 8; ++j) {
                aS[j]  = bfbits(xa * es[j]);
                aV0[j] = bfbits(xa * ev[j*3 + 0]);
                aV1[j] = bfbits(xa * ev[j*3 + 1]);
                aV2[j] = bfbits(xa * ev[j*3 + 2]);
            }
        } else {
            const int a = 4 * (tt - 16) + g;
            const float x0 = bf2f(xvls[er][a*3 + 0]);
            const float x1 = bf2f(xvls[er][a*3 + 1]);
            const float x2 = bf2f(xvls[er][a*3 + 2]);
            #pragma unroll
            for (int j = 0; j < 8; ++j) {
                float p = fmaf(x2, ev[j*3 + 2], fmaf(x1, ev[j*3 + 1], x0 * ev[j*3 + 0]));
                aS[j]  = bfbits(p);
                aV0[j] = bfbits(x0 * es[j]);
                aV1[j] = bfbits(x1 * es[j]);
                aV2[j] = bfbits(x2 * es[j]);
            }
        }

        #pragma unroll
        for (int n = 0; n < 4; ++n)
            accS[n] = __builtin_amdgcn_mfma_f32_16x16x32_bf16(aS, bS[n], accS[n], 0, 0, 0);
        #pragma unroll
        for (int n = 0; n < 2; ++n) {
            accV[0][n] = __builtin_amdgcn_mfma_f32_16x16x32_bf16(aV0, bV[n], accV[0][n], 0, 0, 0);
            accV[1][n] = __builtin_amdgcn_mfma_f32_16x16x32_bf16(aV1, bV[n], accV[1][n], 0, 0, 0);
            accV[2][n] = __builtin_amdgcn_mfma_f32_16x16x32_bf16(aV2, bV[n], accV[2][n], 0, 0, 0);
        }
    }

    // C/D: col = lane&15 (=r), row = g*4 + reg
    #pragma unroll
    for (int reg = 0; reg < 4; ++reg) {
        const int erow = wv * 16 + g * 4 + reg;
        const int node = rowls[erow];
        float* Trow = T + (size_t)node * DN;
        #pragma unroll
        for (int n = 0; n < 4; ++n)
            atomicAdd(Trow + n * 16 + r, accS[n][reg]);
        #pragma unroll
        for (int i = 0; i < 3; ++i) {
            #pragma unroll
            for (int n = 0; n < 2; ++n)
                atomicAdd(Trow + 64 + i * 32 + n * 16 + r, accV[i][n][reg]);  // i-major
        }
    }
}

// ---- node update: out = x + [bf16(x), bf16(T)] @ Wn + bu + deg*bc ----
// T == d_out (accumulator read, final out written). 64 rows/block, 4 waves.
__global__ __launch_bounds__(256) void node_kernel(
    const float* __restrict__ x, float* __restrict__ T,
    const float* __restrict__ deg, const unsigned short* __restrict__ Wn,
    const float* __restrict__ bu, const float* __restrict__ bc)
{
    __shared__ __align__(16) unsigned short A[64][328];  // 160 x-cols | 160 T-cols (bf16)
    const int t = threadIdx.x;
    const int nb = blockIdx.x * 64;

    for (int j = t; j < 64 * 80; j += 256) {
        int m = j / 80, q = j - m * 80;
        int row = nb + m; if (row >= NN) row = NN - 1;
        const float* src = (q < 40) ? (x + (size_t)row * DN + q * 4)
                                    : (T + (size_t)row * DN + (q - 40) * 4);
        const float4 v = *reinterpret_cast<const float4*>(src);
        int o = (q < 40) ? q * 4 : 160 + (q - 40) * 4;
        u16x4 p; p[0] = bfu16(v.x); p[1] = bfu16(v.y); p[2] = bfu16(v.z); p[3] = bfu16(v.w);
        *reinterpret_cast<u16x4*>(&A[m][o]) = p;
    }
    __syncthreads();

    const int lane = t & 63;
    const int wv = t >> 6;
    const int r = lane & 15, g = lane >> 4;
    const int er = wv * 16 + r;

    f32x4 acc[10];
    #pragma unroll
    for (int n = 0; n < 10; ++n) acc[n] = (f32x4){0.f, 0.f, 0.f, 0.f};

    for (int tk = 0; tk < 10; ++tk) {
        const bf16x8 a = *reinterpret_cast<const bf16x8*>(&A[er][32 * tk + 8 * g]);
        #pragma unroll
        for (int n = 0; n < 10; ++n) {
            const bf16x8 b = *reinterpret_cast<const bf16x8*>(Wn + ((size_t)(n * 10 + tk) * 64 + lane) * 8);
            acc[n] = __builtin_amdgcn_mfma_f32_16x16x32_bf16(a, b, acc[n], 0, 0, 0);
        }
    }

    #pragma unroll
    for (int reg = 0; reg < 4; ++reg) {
        const int nrow = nb + wv * 16 + g * 4 + reg;
        if (nrow < NN) {
            const float dg = deg[nrow];
            #pragma unroll
            for (int n = 0; n < 10; ++n) {
                const int c = n * 16 + r;
                const float val = acc[n][reg] + x[(size_t)nrow * DN + c] + bu[c] + dg * bc[c];
                T[(size_t)nrow * DN + c] = val;
            }
        }
    }
}

extern "C" void kernel_launch(void* const* d_in, const int* in_sizes, int n_in,
                              void* d_out, int out_size, void* d_ws, size_t ws_size,
                              hipStream_t stream) {
    const float* xf   = (const float*)d_in[0];
    const int*   eidx = (const int*)d_in[1];
    const float* ea   = (const float*)d_in[2];
    const float* W1 = (const float*)d_in[4];
    const float* W2 = (const float*)d_in[5];
    const float* W3 = (const float*)d_in[6];
    const float* W4 = (const float*)d_in[7];
    const float* Wm = (const float*)d_in[8];
    const float* bm = (const float*)d_in[9];
    const float* Wu = (const float*)d_in[10];
    const float* bu = (const float*)d_in[11];

    float* out = (float*)d_out;   // doubles as tp-accumulator T

    char* ws = (char*)d_ws;
    float*          deg = (float*)ws;                         // 200 KB
    unsigned short* Wbf = (unsigned short*)(ws + (256 << 10)); // 144 KB edge weights
    float*          Wc  = (float*)(ws + (512 << 10));          // 100 KB fp32
    float*          bc  = (float*)(ws + (640 << 10));          // 640 B
    unsigned short* Wn  = (unsigned short*)(ws + (768 << 10)); // 100 KB node weights

    wcomp_kernel<<<100, 256, 0, stream>>>(Wm, bm, Wu, Wc, bc);
    wprep_node_kernel<<<200, 256, 0, stream>>>(Wu, Wc, Wn);
    wprep_edge_kernel<<<288, 256, 0, stream>>>(W1, W2, W3, W4, Wbf);
    zero_kernel<<<(NN * DN + 255) / 256, 256, 0, stream>>>(out, deg);
    edge_kernel<<<NE / 64, 256, 0, stream>>>(xf, eidx, ea, Wbf, out, deg);
    node_kernel<<<(NN + 63) / 64, 256, 0, stream>>>(xf, out, deg, Wn, bu, bc);
}

// Round 6
// 544.771 us; speedup vs baseline: 13.5824x; 1.7738x over previous
//
#include <hip/hip_runtime.h>
#include <hip/hip_bf16.h>

#define NN 50000
#define NE 800000
#define DN 160
#define DE 32
#define NP 50176              /* NN padded to 196*256 */

typedef __attribute__((ext_vector_type(8))) short bf16x8;
typedef __attribute__((ext_vector_type(4))) float f32x4;
typedef __attribute__((ext_vector_type(4))) unsigned short u16x4;

#define R2 0.81649658092772603f   /* sqrt(2/3): W2 rel scale */
#define R4 1.41421356237309515f   /* sqrt(2):   W4 rel scale */
#define SC (1.0f/32.0f)           /* global scale folded into weights */

__device__ __forceinline__ unsigned short bfu16(float f) {
    union { __hip_bfloat16 h; unsigned short s; } u;
    u.h = __float2bfloat16(f);
    return u.s;
}
__device__ __forceinline__ short bfbits(float f) { return (short)bfu16(f); }
__device__ __forceinline__ float bf2f(unsigned short s) {
    union { float f; unsigned int u; } u;
    u.u = ((unsigned int)s) << 16;
    return u.f;
}

// ---- zero T + histogram counters ----
__global__ __launch_bounds__(256) void zero_kernel(float* __restrict__ T,
                                                   int* __restrict__ cnt) {
    int i = blockIdx.x * 256 + threadIdx.x;
    if (i < NN * DN) T[i] = 0.0f;
    if (i < NP) cnt[i] = 0;
}

__global__ __launch_bounds__(256) void hist_kernel(const int* __restrict__ eidx,
                                                   int* __restrict__ cnt) {
    int e = blockIdx.x * 256 + threadIdx.x;
    if (e < NE) atomicAdd(&cnt[eidx[e]], 1);
}

// block-level exclusive scan (256 elems) -> cursor, block sums -> bsum
__global__ __launch_bounds__(256) void scan1_kernel(const int* __restrict__ cnt,
                                                    int* __restrict__ cursor,
                                                    int* __restrict__ bsum) {
    __shared__ int s[256];
    const int t = threadIdx.x;
    const int i = blockIdx.x * 256 + t;
    const int v = cnt[i];
    s[t] = v; __syncthreads();
    for (int off = 1; off < 256; off <<= 1) {
        int u = (t >= off) ? s[t - off] : 0;
        __syncthreads(); s[t] += u; __syncthreads();
    }
    cursor[i] = s[t] - v;
    if (t == 255) bsum[blockIdx.x] = s[255];
}

__global__ __launch_bounds__(256) void scan2_kernel(int* __restrict__ bsum) {
    __shared__ int s[256];
    const int t = threadIdx.x;
    const int v = (t < 196) ? bsum[t] : 0;
    s[t] = v; __syncthreads();
    for (int off = 1; off < 256; off <<= 1) {
        int u = (t >= off) ? s[t - off] : 0;
        __syncthreads(); s[t] += u; __syncthreads();
    }
    if (t < 196) bsum[t] = s[t] - v;
}

__global__ __launch_bounds__(256) void scan3_kernel(int* __restrict__ cursor,
                                                    const int* __restrict__ bsum) {
    int i = blockIdx.x * 256 + threadIdx.x;
    cursor[i] += bsum[blockIdx.x];
}

__global__ __launch_bounds__(256) void scatter_kernel(const int* __restrict__ eidx,
                                                      int* __restrict__ cursor,
                                                      int* __restrict__ sorted) {
    int e = blockIdx.x * 256 + threadIdx.x;
    if (e < NE) {
        int pos = atomicAdd(&cursor[eidx[e]], 1);
        sorted[pos] = e;
    }
}

// ---- edge-TP weights: bf16, pre-scaled, MFMA 16x16x32 B-frag layout ----
__global__ __launch_bounds__(256) void wprep_edge_kernel(
    const float* __restrict__ W1, const float* __restrict__ W2,
    const float* __restrict__ W3, const float* __restrict__ W4,
    unsigned short* __restrict__ Wbf)
{
    int id = blockIdx.x * 256 + threadIdx.x;   // 73728 total
    float w;
    if (id < 49152) {
        int j = id & 7, l = (id >> 3) & 63, t = (id >> 9) % 24, n16 = id / 12288;
        int c = n16 * 16 + (l & 15);
        int k = 32 * t + 8 * (l >> 4) + j;
        if (k < 512) { int a = k >> 3, b = k & 7; w = W1[(a*8+b)*64 + c] * SC; }
        else { int k2 = k - 512; int a = k2 >> 3, b = k2 & 7; w = W2[(a*8+b)*64 + c] * (R2*SC); }
    } else {
        int id2 = id - 49152;
        int j = id2 & 7, l = (id2 >> 3) & 63, t = (id2 >> 9) % 24, n16 = id2 / 12288;
        int c = n16 * 16 + (l & 15);
        int k = 32 * t + 8 * (l >> 4) + j;
        if (k < 512) { int a = k >> 3, b = k & 7; w = W3[(a*8+b)*32 + c] * SC; }
        else { int k2 = k - 512; int a = k2 >> 3, b = k2 & 7; w = W4[(a*8+b)*32 + c] * (R4*SC); }
    }
    Wbf[id] = bfu16(w);
}

// ---- Wc = Wm @ Wu_bot (fp32), bc = bm @ Wu_bot ----
__global__ __launch_bounds__(256) void wcomp_kernel(
    const float* __restrict__ Wm, const float* __restrict__ bm,
    const float* __restrict__ Wu, float* __restrict__ Wc, float* __restrict__ bc)
{
    int id = blockIdx.x * 256 + threadIdx.x;
    if (id < 160 * 160) {
        int k = id / 160, c = id % 160;
        float s = 0.0f;
        for (int h = 0; h < 160; ++h) s = fmaf(Wm[k*160 + h], Wu[(160 + h)*160 + c], s);
        Wc[id] = s;
    }
    if (id < 160) {
        float s = 0.0f;
        for (int h = 0; h < 160; ++h) s = fmaf(bm[h], Wu[(160 + h)*160 + id], s);
        bc[id] = s;
    }
}

// ---- node-GEMM weights: [Wu_top(160); Wc permuted to T's i-major layout] ----
__global__ __launch_bounds__(256) void wprep_node_kernel(
    const float* __restrict__ Wu, const float* __restrict__ Wc,
    unsigned short* __restrict__ Wn)
{
    int id = blockIdx.x * 256 + threadIdx.x;   // 51200 total
    if (id >= 51200) return;
    int j = id & 7, l = (id >> 3) & 63, tn = id >> 9;  // tn = n16*10 + tk
    int tk = tn % 10, n16 = tn / 10;
    int c = n16 * 16 + (l & 15);
    int k = 32 * tk + 8 * (l >> 4) + j;
    float w;
    if (k < 160) {
        w = Wu[k * 160 + c];
    } else {
        int tcol = k - 160;  // T col: [0,64)=s ; 64+i*32+cc (i-major v)
        int orig = (tcol < 64) ? tcol : 64 + ((tcol - 64) & 31) * 3 + ((tcol - 64) >> 5);
        w = Wc[orig * 160 + c];
    }
    Wn[id] = bfu16(w);
}

// ---- per-edge TP via MFMA on dest-sorted edges; LDS segment-reduce;
//      plain store for interior nodes, atomicAdd only for boundary runs ----
__global__ __launch_bounds__(256, 3) void edge_kernel(
    const float* __restrict__ x, const int* __restrict__ eidx,
    const float* __restrict__ ea, const unsigned short* __restrict__ Wbf,
    const int* __restrict__ sorted, float* __restrict__ T)
{
    __shared__ __align__(16) char smem[64 * 161 * 4];  // stage1: xs|xv|e ; stage2: acc[64][161]
    __shared__ int rowls[64];
    __shared__ int colls[64];
    __shared__ int sels[64];

    float* xsls = (float*)smem;                                    // [64][66] fp32
    unsigned short* xvls = (unsigned short*)(smem + 64*66*4);      // [64][100] bf16
    float* els = (float*)(smem + 64*66*4 + 64*100*2);              // [64][33] fp32

    const int t = threadIdx.x;
    const int base = blockIdx.x * 64;

    if (t < 64) {
        const int se = sorted[base + t];
        sels[t] = se;
        rowls[t] = eidx[se];
        colls[t] = eidx[NE + se];
    }
    __syncthreads();

    for (int j = t; j < 64 * 40; j += 256) {
        int m = j / 40, q = j - m * 40;
        const float4 v = *reinterpret_cast<const float4*>(x + (size_t)colls[m] * DN + q * 4);
        if (q < 16) {
            xsls[m*66 + q*4+0] = v.x; xsls[m*66 + q*4+1] = v.y;
            xsls[m*66 + q*4+2] = v.z; xsls[m*66 + q*4+3] = v.w;
        } else {
            u16x4 p; p[0] = bfu16(v.x); p[1] = bfu16(v.y); p[2] = bfu16(v.z); p[3] = bfu16(v.w);
            *reinterpret_cast<u16x4*>(&xvls[m*100 + q*4 - 64]) = p;
        }
    }
    for (int j = t; j < 64 * 8; j += 256) {
        int m = j >> 3, q = j & 7;
        // FIX(R5->R6): edge attrs must come from the SORTED edge id, not slot pos
        const float4 v = *reinterpret_cast<const float4*>(ea + (size_t)sels[m] * DE + q * 4);
        els[m*33 + q*4+0] = v.x; els[m*33 + q*4+1] = v.y;
        els[m*33 + q*4+2] = v.z; els[m*33 + q*4+3] = v.w;
    }
    __syncthreads();

    const int lane = t & 63;
    const int wv = t >> 6;        // 0..3
    const int r = lane & 15;      // A row / B col / C col
    const int g = lane >> 4;      // k-group
    const int er = wv * 16 + r;   // edge owning this lane's A row

    float es[8], ev[24];
    #pragma unroll
    for (int j = 0; j < 8; ++j) es[j] = els[er*33 + j];
    #pragma unroll
    for (int j = 0; j < 24; ++j) ev[j] = els[er*33 + 8 + j];

    f32x4 accS[4], accV[3][2];
    #pragma unroll
    for (int n = 0; n < 4; ++n) accS[n] = (f32x4){0.f, 0.f, 0.f, 0.f};
    #pragma unroll
    for (int i = 0; i < 3; ++i)
        #pragma unroll
        for (int n = 0; n < 2; ++n) accV[i][n] = (f32x4){0.f, 0.f, 0.f, 0.f};

    const unsigned short* Ws = Wbf;          // s-part
    const unsigned short* Wv = Wbf + 49152;  // v-part

    for (int tt = 0; tt < 24; ++tt) {
        bf16x8 bS[4], bV[2];
        #pragma unroll
        for (int n = 0; n < 4; ++n)
            bS[n] = *reinterpret_cast<const bf16x8*>(Ws + ((size_t)(n * 24 + tt) * 64 + lane) * 8);
        #pragma unroll
        for (int n = 0; n < 2; ++n)
            bV[n] = *reinterpret_cast<const bf16x8*>(Wv + ((size_t)(n * 24 + tt) * 64 + lane) * 8);

        bf16x8 aS, aV0, aV1, aV2;
        if (tt < 16) {
            const int a = 4 * tt + g;
            const float xa = xsls[er*66 + a];
            #pragma unroll
            for (int j = 0; j < 8; ++j) {
                aS[j]  = bfbits(xa * es[j]);
                aV0[j] = bfbits(xa * ev[j*3 + 0]);
                aV1[j] = bfbits(xa * ev[j*3 + 1]);
                aV2[j] = bfbits(xa * ev[j*3 + 2]);
            }
        } else {
            const int a = 4 * (tt - 16) + g;
            const float x0 = bf2f(xvls[er*100 + a*3 + 0]);
            const float x1 = bf2f(xvls[er*100 + a*3 + 1]);
            const float x2 = bf2f(xvls[er*100 + a*3 + 2]);
            #pragma unroll
            for (int j = 0; j < 8; ++j) {
                float p = fmaf(x2, ev[j*3 + 2], fmaf(x1, ev[j*3 + 1], x0 * ev[j*3 + 0]));
                aS[j]  = bfbits(p);
                aV0[j] = bfbits(x0 * es[j]);
                aV1[j] = bfbits(x1 * es[j]);
                aV2[j] = bfbits(x2 * es[j]);
            }
        }

        #pragma unroll
        for (int n = 0; n < 4; ++n)
            accS[n] = __builtin_amdgcn_mfma_f32_16x16x32_bf16(aS, bS[n], accS[n], 0, 0, 0);
        #pragma unroll
        for (int n = 0; n < 2; ++n) {
            accV[0][n] = __builtin_amdgcn_mfma_f32_16x16x32_bf16(aV0, bV[n], accV[0][n], 0, 0, 0);
            accV[1][n] = __builtin_amdgcn_mfma_f32_16x16x32_bf16(aV1, bV[n], accV[1][n], 0, 0, 0);
            accV[2][n] = __builtin_amdgcn_mfma_f32_16x16x32_bf16(aV2, bV[n], accV[2][n], 0, 0, 0);
        }
    }

    __syncthreads();   // done with xs/xv/e staging; reuse smem for acc
    float* accw = (float*)smem;  // [64][161]

    // C/D: col = lane&15 (=r), row = g*4 + reg
    #pragma unroll
    for (int reg = 0; reg < 4; ++reg) {
        const int erow = wv * 16 + g * 4 + reg;
        #pragma unroll
        for (int n = 0; n < 4; ++n)
            accw[erow*161 + n*16 + r] = accS[n][reg];
        #pragma unroll
        for (int i = 0; i < 3; ++i)
            #pragma unroll
            for (int n = 0; n < 2; ++n)
                accw[erow*161 + 64 + i*32 + n*16 + r] = accV[i][n][reg];  // i-major
    }
    __syncthreads();

    // segment-reduce the 64 sorted edges; flush per run
    if (t < DN) {
        const int col = t;
        float s = 0.0f;
        int rstart = 0;
        for (int e = 0; e < 64; ++e) {
            s += accw[e*161 + col];
            if (e == 63 || rowls[e] != rowls[e + 1]) {
                float* dst = T + (size_t)rowls[e] * DN + col;
                if (rstart == 0 || e == 63) atomicAdd(dst, s);  // boundary run
                else *dst = s;                                   // interior: exclusive
                s = 0.0f; rstart = e + 1;
            }
        }
    }
}

// ---- node update: out = x + [bf16(x), bf16(T)] @ Wn + bu + deg*bc ----
__global__ __launch_bounds__(256) void node_kernel(
    const float* __restrict__ x, float* __restrict__ T,
    const int* __restrict__ cnt, const unsigned short* __restrict__ Wn,
    const float* __restrict__ bu, const float* __restrict__ bc)
{
    __shared__ __align__(16) unsigned short A[64][328];  // 160 x | 160 T (bf16)
    const int t = threadIdx.x;
    const int nb = blockIdx.x * 64;

    for (int j = t; j < 64 * 80; j += 256) {
        int m = j / 80, q = j - m * 80;
        int row = nb + m; if (row >= NN) row = NN - 1;
        const float* src = (q < 40) ? (x + (size_t)row * DN + q * 4)
                                    : (T + (size_t)row * DN + (q - 40) * 4);
        const float4 v = *reinterpret_cast<const float4*>(src);
        int o = (q < 40) ? q * 4 : 160 + (q - 40) * 4;
        u16x4 p; p[0] = bfu16(v.x); p[1] = bfu16(v.y); p[2] = bfu16(v.z); p[3] = bfu16(v.w);
        *reinterpret_cast<u16x4*>(&A[m][o]) = p;
    }
    __syncthreads();

    const int lane = t & 63;
    const int wv = t >> 6;
    const int r = lane & 15, g = lane >> 4;
    const int er = wv * 16 + r;

    f32x4 acc[10];
    #pragma unroll
    for (int n = 0; n < 10; ++n) acc[n] = (f32x4){0.f, 0.f, 0.f, 0.f};

    for (int tk = 0; tk < 10; ++tk) {
        const bf16x8 a = *reinterpret_cast<const bf16x8*>(&A[er][32 * tk + 8 * g]);
        #pragma unroll
        for (int n = 0; n < 10; ++n) {
            const bf16x8 b = *reinterpret_cast<const bf16x8*>(Wn + ((size_t)(n * 10 + tk) * 64 + lane) * 8);
            acc[n] = __builtin_amdgcn_mfma_f32_16x16x32_bf16(a, b, acc[n], 0, 0, 0);
        }
    }

    #pragma unroll
    for (int reg = 0; reg < 4; ++reg) {
        const int nrow = nb + wv * 16 + g * 4 + reg;
        if (nrow < NN) {
            const float dg = (float)cnt[nrow];
            #pragma unroll
            for (int n = 0; n < 10; ++n) {
                const int c = n * 16 + r;
                T[(size_t)nrow * DN + c] =
                    acc[n][reg] + x[(size_t)nrow * DN + c] + bu[c] + dg * bc[c];
            }
        }
    }
}

extern "C" void kernel_launch(void* const* d_in, const int* in_sizes, int n_in,
                              void* d_out, int out_size, void* d_ws, size_t ws_size,
                              hipStream_t stream) {
    const float* xf   = (const float*)d_in[0];
    const int*   eidx = (const int*)d_in[1];
    const float* ea   = (const float*)d_in[2];
    const float* W1 = (const float*)d_in[4];
    const float* W2 = (const float*)d_in[5];
    const float* W3 = (const float*)d_in[6];
    const float* W4 = (const float*)d_in[7];
    const float* Wm = (const float*)d_in[8];
    const float* bm = (const float*)d_in[9];
    const float* Wu = (const float*)d_in[10];
    const float* bu = (const float*)d_in[11];

    float* out = (float*)d_out;   // doubles as tp-accumulator T

    char* ws = (char*)d_ws;
    int*            cnt    = (int*)ws;                              // 256 KB slot
    int*            cursor = (int*)(ws + (256 << 10));              // 256 KB slot
    int*            sorted = (int*)(ws + (512 << 10));              // 3.2 MB
    int*            bsum   = (int*)(ws + (4096 << 10));             // 1 KB
    unsigned short* Wbf    = (unsigned short*)(ws + (4112 << 10));  // 144 KB
    float*          Wc     = (float*)(ws + (4288 << 10));           // 100 KB
    float*          bc     = (float*)(ws + (4416 << 10));           // 640 B
    unsigned short* Wn     = (unsigned short*)(ws + (4432 << 10));  // 100 KB

    wcomp_kernel<<<100, 256, 0, stream>>>(Wm, bm, Wu, Wc, bc);
    wprep_node_kernel<<<200, 256, 0, stream>>>(Wu, Wc, Wn);
    wprep_edge_kernel<<<288, 256, 0, stream>>>(W1, W2, W3, W4, Wbf);
    zero_kernel<<<(NN * DN + 255) / 256, 256, 0, stream>>>(out, cnt);
    hist_kernel<<<NE / 256, 256, 0, stream>>>(eidx, cnt);
    scan1_kernel<<<NP / 256, 256, 0, stream>>>(cnt, cursor, bsum);
    scan2_kernel<<<1, 256, 0, stream>>>(bsum);
    scan3_kernel<<<NP / 256, 256, 0, stream>>>(cursor, bsum);
    scatter_kernel<<<NE / 256, 256, 0, stream>>>(eidx, cursor, sorted);
    edge_kernel<<<NE / 64, 256, 0, stream>>>(xf, eidx, ea, Wbf, sorted, out);
    node_kernel<<<(NN + 63) / 64, 256, 0, stream>>>(xf, out, cnt, Wn, bu, bc);
}